// Round 9
// baseline (1681.922 us; speedup 1.0000x reference)
//
#include <hip/hip_runtime.h>

#define VV 50257
#define DD 50
#define TT 1024
#define BB 1024

__device__ __forceinline__ float rl(float v, int lane) {
    return __int_as_float(__builtin_amdgcn_readlane(__float_as_int(v), lane));
}
__device__ __forceinline__ float sigmf(float x) { return 1.0f / (1.0f + __expf(-x)); }
__device__ __forceinline__ float tanhf_fast(float x) {
    float e = __expf(-2.0f * fabsf(x));
    return copysignf((1.0f - e) / (1.0f + e), x);
}

// P1[v][j] = b1[0][j] + sum_d emb[v][d] * kx1[d][j]   (one-time, ~0.5 GFLOP)
__global__ void proj_emb(const float* __restrict__ emb, const float* __restrict__ kx1,
                         const float* __restrict__ b1, float* __restrict__ P1) {
    int j = threadIdx.x;             // 0..95
    int v0 = blockIdx.x * 8;
    #pragma unroll 1
    for (int vv = 0; vv < 8; ++vv) {
        int v = v0 + vv;
        if (v >= VV) return;
        float acc = b1[j];
        #pragma unroll
        for (int d = 0; d < DD; ++d)
            acc += emb[v * DD + d] * kx1[d * 96 + j];
        P1[v * 96 + j] = acc;
    }
}

// FOUR waves, TWO rows per block (512 blocks = 2048 waves = 2/SIMD).
// Key changes vs r8 (1282us): (a) NO readlane broadcasts in the hot loop --
// state is broadcast via uniform-address ds_read_b128 from small LDS buffers
// (kills the v_readlane->SGPR->VALU hazard chain); (b) no wave holds more
// than 96 weight floats (under the allocator's observed ~150 arch-VGPR cap,
// so nothing spills to AGPRs -> no v_accvgpr_read tax); (c) weights amortize
// over 2 rows. Skew/ring/guards are r7's verified scheme (absmax 0.0).
// Roles & skew at iter t:
//  W0: kh2 k=0..31 partial of m(t-2) -> part0      (pre-barrier)
//  W1: kh2 k=32..63 partial in regs (pre); combine + gates -> h2(t-2) (post)
//  W2: GRU1: h1(t) from h1(t-1), writes h1s[t&1]   (pre), t<TT
//  W3: x(t-1) = h1(t-1)*kx2 + b2[0] -> xq[(t-1)&1] (pre)
// LDS safety: h2s written G(t), read P(t+1) (1 barrier). h1s double-buffered
// by parity: written P(t) slot t&1, read P(t+1)/P(t+2)? -- read slot (t+1)&1
// = h1(t-1) (2 barriers after write). xq slot (t-1)&1 written P(t), read
// G(t+1) (2 barriers), overwritten P(t+2) (after the read). part0 written
// P(t), read G(t) (1 barrier), rewritten P(t+1) (after G(t) barrier).
__global__ __launch_bounds__(256, 2)
void rnn_main(const int* __restrict__ tokens, const float* __restrict__ P1,
              const float* __restrict__ kh1, const float* __restrict__ b1,
              const float* __restrict__ kx2, const float* __restrict__ kh2,
              const float* __restrict__ b2, const float* __restrict__ wg,
              const float* __restrict__ bg, const float* __restrict__ wd,
              const float* __restrict__ bd, float* __restrict__ out) {
    const int lane = threadIdx.x & 63;
    const int wv   = threadIdx.x >> 6;
    const int row0 = blockIdx.x * 2;
    const int row1 = row0 + 1;
    const int l32  = lane & 31;
    const int* __restrict__ trow0 = tokens + row0 * TT;
    const int* __restrict__ trow1 = tokens + row1 * TT;

    __shared__ float  h2s[2][64];      // current h2 per row (single-buffered)
    __shared__ float  h1s[2][2][32];   // [parity][row][unit]
    __shared__ float4 xq[2][2][64];    // [slot][row][lane] x-triples
    __shared__ float4 part0[2][64];    // W0's m-partial per row

    if (threadIdx.x < 64) {
        h2s[0][threadIdx.x] = 0.f; h2s[1][threadIdx.x] = 0.f;
    } else if (threadIdx.x < 96) {
        int i = threadIdx.x - 64;
        h1s[0][0][i] = 0.f; h1s[0][1][i] = 0.f;
        h1s[1][0][i] = 0.f; h1s[1][1][i] = 0.f;
    }

    // ---- per-wave weight columns (max 96 floats -> stays in arch VGPRs) ----
    float w[96];
    float f0 = 0.f, f1 = 0.f, f2 = 0.f;
    if (wv == 0) {
        #pragma unroll
        for (int k = 0; k < 32; ++k) {
            w[3 * k]     = kh2[k * 192 + lane];
            w[3 * k + 1] = kh2[k * 192 + 64 + lane];
            w[3 * k + 2] = kh2[k * 192 + 128 + lane];
        }
    } else if (wv == 1) {
        #pragma unroll
        for (int k = 0; k < 32; ++k) {
            w[3 * k]     = kh2[(32 + k) * 192 + lane];
            w[3 * k + 1] = kh2[(32 + k) * 192 + 64 + lane];
            w[3 * k + 2] = kh2[(32 + k) * 192 + 128 + lane];
        }
        f0 = b2[192 + lane]; f1 = b2[256 + lane]; f2 = b2[320 + lane];
    } else if (wv == 2) {
        #pragma unroll
        for (int k = 0; k < 32; ++k) {
            w[k]      = kh1[k * 96 + lane];                       // z|r col
            w[32 + k] = (lane < 32) ? kh1[k * 96 + 64 + lane] : 0.f;  // h col
        }
        f0 = b1[96 + lane];
        f1 = (lane < 32) ? b1[160 + lane] : 0.f;
    } else {
        #pragma unroll
        for (int k = 0; k < 32; ++k) {
            w[3 * k]     = kx2[k * 192 + lane];
            w[3 * k + 1] = kx2[k * 192 + 64 + lane];
            w[3 * k + 2] = kx2[k * 192 + 128 + lane];
        }
        f0 = b2[lane]; f1 = b2[64 + lane]; f2 = b2[128 + lane];
    }

    float h2r0 = 0.f, h2r1 = 0.f;                       // W1 state per row
    float mz0, mr0, mh0, mz1, mr1, mh1;                 // W1 partials (P->G)
    float pz0 = 0.f, pr0 = 0.f, ph0 = 0.f, pz1 = 0.f, pr1 = 0.f, ph1 = 0.f;
    int tok10 = 0, tok11 = 0;
    if (wv == 2) {
        const float* __restrict__ p0 = P1 + trow0[0] * 96;
        const float* __restrict__ p1 = P1 + trow1[0] * 96;
        pz0 = p0[l32]; pr0 = p0[32 + l32]; ph0 = p0[64 + l32];
        pz1 = p1[l32]; pr1 = p1[32 + l32]; ph1 = p1[64 + l32];
        tok10 = trow0[1]; tok11 = trow1[1];
    }

    __syncthreads();

    #pragma unroll 1
    for (int t = 0; t <= TT + 1; ++t) {
        const int par = (t + 1) & 1;   // parity holding h1(t-1); also xq slot for x(t-1)
        // ---------------- P phase ----------------
        if (wv == 0) {
            float az0 = 0.f, ar0 = 0.f, ah0 = 0.f;
            #pragma unroll
            for (int kc = 0; kc < 8; ++kc) {
                const float4 hb = *reinterpret_cast<const float4*>(&h2s[0][kc * 4]);
                const int b = kc * 12;
                az0 += hb.x * w[b];     ar0 += hb.x * w[b + 1];  ah0 += hb.x * w[b + 2];
                az0 += hb.y * w[b + 3]; ar0 += hb.y * w[b + 4];  ah0 += hb.y * w[b + 5];
                az0 += hb.z * w[b + 6]; ar0 += hb.z * w[b + 7];  ah0 += hb.z * w[b + 8];
                az0 += hb.w * w[b + 9]; ar0 += hb.w * w[b + 10]; ah0 += hb.w * w[b + 11];
            }
            part0[0][lane] = make_float4(az0, ar0, ah0, 0.f);
            float az1 = 0.f, ar1 = 0.f, ah1 = 0.f;
            #pragma unroll
            for (int kc = 0; kc < 8; ++kc) {
                const float4 hb = *reinterpret_cast<const float4*>(&h2s[1][kc * 4]);
                const int b = kc * 12;
                az1 += hb.x * w[b];     ar1 += hb.x * w[b + 1];  ah1 += hb.x * w[b + 2];
                az1 += hb.y * w[b + 3]; ar1 += hb.y * w[b + 4];  ah1 += hb.y * w[b + 5];
                az1 += hb.z * w[b + 6]; ar1 += hb.z * w[b + 7];  ah1 += hb.z * w[b + 8];
                az1 += hb.w * w[b + 9]; ar1 += hb.w * w[b + 10]; ah1 += hb.w * w[b + 11];
            }
            part0[1][lane] = make_float4(az1, ar1, ah1, 0.f);
        } else if (wv == 1) {
            mz0 = f0; mr0 = f1; mh0 = f2;
            #pragma unroll
            for (int kc = 0; kc < 8; ++kc) {
                const float4 hb = *reinterpret_cast<const float4*>(&h2s[0][32 + kc * 4]);
                const int b = kc * 12;
                mz0 += hb.x * w[b];     mr0 += hb.x * w[b + 1];  mh0 += hb.x * w[b + 2];
                mz0 += hb.y * w[b + 3]; mr0 += hb.y * w[b + 4];  mh0 += hb.y * w[b + 5];
                mz0 += hb.z * w[b + 6]; mr0 += hb.z * w[b + 7];  mh0 += hb.z * w[b + 8];
                mz0 += hb.w * w[b + 9]; mr0 += hb.w * w[b + 10]; mh0 += hb.w * w[b + 11];
            }
            mz1 = f0; mr1 = f1; mh1 = f2;
            #pragma unroll
            for (int kc = 0; kc < 8; ++kc) {
                const float4 hb = *reinterpret_cast<const float4*>(&h2s[1][32 + kc * 4]);
                const int b = kc * 12;
                mz1 += hb.x * w[b];     mr1 += hb.x * w[b + 1];  mh1 += hb.x * w[b + 2];
                mz1 += hb.y * w[b + 3]; mr1 += hb.y * w[b + 4];  mh1 += hb.y * w[b + 5];
                mz1 += hb.z * w[b + 6]; mr1 += hb.z * w[b + 7];  mh1 += hb.z * w[b + 8];
                mz1 += hb.w * w[b + 9]; mr1 += hb.w * w[b + 10]; mh1 += hb.w * w[b + 11];
            }
        } else if (wv == 2) {
            if (t < TT) {
                // prefetch p(t+1) rows and tokens(t+2)
                const float* __restrict__ pn0 = P1 + tok10 * 96;
                const float* __restrict__ pn1 = P1 + tok11 * 96;
                float pzn0 = pn0[l32], prn0 = pn0[32 + l32], phn0 = pn0[64 + l32];
                float pzn1 = pn1[l32], prn1 = pn1[32 + l32], phn1 = pn1[64 + l32];
                int t2 = (t + 2 < TT) ? (t + 2) : (TT - 1);
                int tokn0 = trow0[t2], tokn1 = trow1[t2];
                // row 0: h1(t-1) -> h1(t)
                float az = f0, ah = f1;
                #pragma unroll
                for (int kc = 0; kc < 8; ++kc) {
                    const float4 hb = *reinterpret_cast<const float4*>(&h1s[par][0][kc * 4]);
                    az += hb.x * w[kc * 4];     ah += hb.x * w[32 + kc * 4];
                    az += hb.y * w[kc * 4 + 1]; ah += hb.y * w[32 + kc * 4 + 1];
                    az += hb.z * w[kc * 4 + 2]; ah += hb.z * w[32 + kc * 4 + 2];
                    az += hb.w * w[kc * 4 + 3]; ah += hb.w * w[32 + kc * 4 + 3];
                }
                float hp  = h1s[par][0][l32];
                float ra  = __shfl_xor(az, 32);
                float z1  = sigmf(pz0 + az);
                float g1  = sigmf(pr0 + ra);
                float hh1 = tanhf_fast(ph0 + g1 * ah);
                float hn0 = z1 * hp + (1.f - z1) * hh1;
                if (lane < 32) h1s[t & 1][0][lane] = hn0;
                // row 1
                float bz = f0, bh = f1;
                #pragma unroll
                for (int kc = 0; kc < 8; ++kc) {
                    const float4 hb = *reinterpret_cast<const float4*>(&h1s[par][1][kc * 4]);
                    bz += hb.x * w[kc * 4];     bh += hb.x * w[32 + kc * 4];
                    bz += hb.y * w[kc * 4 + 1]; bh += hb.y * w[32 + kc * 4 + 1];
                    bz += hb.z * w[kc * 4 + 2]; bh += hb.z * w[32 + kc * 4 + 2];
                    bz += hb.w * w[kc * 4 + 3]; bh += hb.w * w[32 + kc * 4 + 3];
                }
                float hq  = h1s[par][1][l32];
                float rb  = __shfl_xor(bz, 32);
                float y1  = sigmf(pz1 + bz);
                float g2  = sigmf(pr1 + rb);
                float hh2 = tanhf_fast(ph1 + g2 * bh);
                float hn1 = y1 * hq + (1.f - y1) * hh2;
                if (lane < 32) h1s[t & 1][1][lane] = hn1;
                pz0 = pzn0; pr0 = prn0; ph0 = phn0; tok10 = tokn0;
                pz1 = pzn1; pr1 = prn1; ph1 = phn1; tok11 = tokn1;
            }
        } else {
            // x(t-1) = h1(t-1)*kx2 + b2[0] -> xq[par]
            float xz0 = f0, xr0 = f1, xh0 = f2;
            #pragma unroll
            for (int kc = 0; kc < 8; ++kc) {
                const float4 hb = *reinterpret_cast<const float4*>(&h1s[par][0][kc * 4]);
                const int b = kc * 12;
                xz0 += hb.x * w[b];     xr0 += hb.x * w[b + 1];  xh0 += hb.x * w[b + 2];
                xz0 += hb.y * w[b + 3]; xr0 += hb.y * w[b + 4];  xh0 += hb.y * w[b + 5];
                xz0 += hb.z * w[b + 6]; xr0 += hb.z * w[b + 7];  xh0 += hb.z * w[b + 8];
                xz0 += hb.w * w[b + 9]; xr0 += hb.w * w[b + 10]; xh0 += hb.w * w[b + 11];
            }
            xq[par][0][lane] = make_float4(xz0, xr0, xh0, 0.f);
            float xz1 = f0, xr1 = f1, xh1 = f2;
            #pragma unroll
            for (int kc = 0; kc < 8; ++kc) {
                const float4 hb = *reinterpret_cast<const float4*>(&h1s[par][1][kc * 4]);
                const int b = kc * 12;
                xz1 += hb.x * w[b];     xr1 += hb.x * w[b + 1];  xh1 += hb.x * w[b + 2];
                xz1 += hb.y * w[b + 3]; xr1 += hb.y * w[b + 4];  xh1 += hb.y * w[b + 5];
                xz1 += hb.z * w[b + 6]; xr1 += hb.z * w[b + 7];  xh1 += hb.z * w[b + 8];
                xz1 += hb.w * w[b + 9]; xr1 += hb.w * w[b + 10]; xh1 += hb.w * w[b + 11];
            }
            xq[par][1][lane] = make_float4(xz1, xr1, xh1, 0.f);
        }
        __syncthreads();
        // ---------------- G phase ----------------
        if (wv == 1 && t >= 2) {
            float4 pa = part0[0][lane];
            float4 x  = xq[t & 1][0][lane];          // x(t-2)
            float z2  = sigmf(x.x + pa.x + mz0);
            float r2  = sigmf(x.y + pa.y + mr0);
            float hh  = tanhf_fast(x.z + r2 * (pa.z + mh0));
            h2r0 = z2 * h2r0 + (1.f - z2) * hh;
            h2s[0][lane] = h2r0;
            float4 pb = part0[1][lane];
            float4 y  = xq[t & 1][1][lane];
            float z3  = sigmf(y.x + pb.x + mz1);
            float r3  = sigmf(y.y + pb.y + mr1);
            float hg  = tanhf_fast(y.z + r3 * (pb.z + mh1));
            h2r1 = z3 * h2r1 + (1.f - z3) * hg;
            h2s[1][lane] = h2r1;
        }
        __syncthreads();
    }

    // ---- tail: GLU + dense head on W1 (holds h2(TT-1) for both rows) ----
    if (wv == 1) {
        float a0 = bg[lane], a1 = bg[64 + lane], a2 = bg[128 + lane], a3 = bg[192 + lane];
        #pragma unroll
        for (int k = 0; k < 64; ++k) {
            float s = rl(h2r0, k);
            a0 += s * wg[k * 256 + lane];
            a1 += s * wg[k * 256 + 64 + lane];
            a2 += s * wg[k * 256 + 128 + lane];
            a3 += s * wg[k * 256 + 192 + lane];
        }
        float g = a0 * sigmf(a2) * wd[lane] + a1 * sigmf(a3) * wd[64 + lane];
        g += __shfl_xor(g, 32); g += __shfl_xor(g, 16); g += __shfl_xor(g, 8);
        g += __shfl_xor(g, 4);  g += __shfl_xor(g, 2);  g += __shfl_xor(g, 1);
        if (lane == 0) out[row0] = sigmf(g + bd[0]);

        float c0 = bg[lane], c1 = bg[64 + lane], c2 = bg[128 + lane], c3 = bg[192 + lane];
        #pragma unroll
        for (int k = 0; k < 64; ++k) {
            float s = rl(h2r1, k);
            c0 += s * wg[k * 256 + lane];
            c1 += s * wg[k * 256 + 64 + lane];
            c2 += s * wg[k * 256 + 128 + lane];
            c3 += s * wg[k * 256 + 192 + lane];
        }
        float g1 = c0 * sigmf(c2) * wd[lane] + c1 * sigmf(c3) * wd[64 + lane];
        g1 += __shfl_xor(g1, 32); g1 += __shfl_xor(g1, 16); g1 += __shfl_xor(g1, 8);
        g1 += __shfl_xor(g1, 4);  g1 += __shfl_xor(g1, 2);  g1 += __shfl_xor(g1, 1);
        if (lane == 0) out[row1] = sigmf(g1 + bd[0]);
    }
}

extern "C" void kernel_launch(void* const* d_in, const int* in_sizes, int n_in,
                              void* d_out, int out_size, void* d_ws, size_t ws_size,
                              hipStream_t stream) {
    const int*   tokens = (const int*)d_in[0];
    const float* emb = (const float*)d_in[1];
    const float* kx1 = (const float*)d_in[2];
    const float* kh1 = (const float*)d_in[3];
    const float* b1  = (const float*)d_in[4];
    const float* kx2 = (const float*)d_in[5];
    const float* kh2 = (const float*)d_in[6];
    const float* b2  = (const float*)d_in[7];
    const float* wg  = (const float*)d_in[8];
    const float* bg  = (const float*)d_in[9];
    const float* wd  = (const float*)d_in[10];
    const float* bd  = (const float*)d_in[11];
    float* out = (float*)d_out;
    float* P1  = (float*)d_ws;   // needs 50257*96*4 = 19.3 MB of workspace

    proj_emb<<<(VV + 7) / 8, 96, 0, stream>>>(emb, kx1, b1, P1);
    rnn_main<<<BB / 2, 256, 0, stream>>>(tokens, P1, kh1, b1, kx2, kh2, b2,
                                         wg, bg, wd, bd, out);
}

// Round 10
// 1458.241 us; speedup vs baseline: 1.1534x; 1.1534x over previous
//
#include <hip/hip_runtime.h>

#define VV 50257
#define DD 50
#define TT 1024
#define BB 1024

typedef float v2f __attribute__((ext_vector_type(2)));
typedef float v4f __attribute__((ext_vector_type(4)));

__device__ __forceinline__ float rl(float v, int lane) {
    return __int_as_float(__builtin_amdgcn_readlane(__float_as_int(v), lane));
}
__device__ __forceinline__ float sigmf(float x) { return 1.0f / (1.0f + __expf(-x)); }
__device__ __forceinline__ float tanhf_fast(float x) {
    float e = __expf(-2.0f * fabsf(x));
    return copysignf((1.0f - e) / (1.0f + e), x);
}
__device__ __forceinline__ v2f mk2(float a, float b) { v2f r; r.x = a; r.y = b; return r; }
// packed fp32: 2 MACs per instruction (VOP3P). acc.[lo,hi] += s.[lo,hi]*w.[lo,hi]
__device__ __forceinline__ void pkfma(v2f& a, v2f s, v2f w) {
    asm("v_pk_fma_f32 %0, %1, %2, %0" : "+v"(a) : "v"(s), "v"(w));
}

// P1[v][j] = b1[0][j] + sum_d emb[v][d] * kx1[d][j]   (one-time, ~0.5 GFLOP)
__global__ void proj_emb(const float* __restrict__ emb, const float* __restrict__ kx1,
                         const float* __restrict__ b1, float* __restrict__ P1) {
    int j = threadIdx.x;             // 0..95
    int v0 = blockIdx.x * 8;
    #pragma unroll 1
    for (int vv = 0; vv < 8; ++vv) {
        int v = v0 + vv;
        if (v >= VV) return;
        float acc = b1[j];
        #pragma unroll
        for (int d = 0; d < DD; ++d)
            acc += emb[v * DD + d] * kx1[d * 96 + j];
        P1[v * 96 + j] = acc;
    }
}

// FOUR waves per row (r7's verified skew; absmax 0.0), rebuilt around:
//  (a) v_pk_fma_f32: 2 MACs/instr -> GRU2-rec = 48 pk/wave instead of 192 fma;
//  (b) uniform-address ds_read_b128 broadcasts of state (each float4 = two
//      ready pk operand pairs; kills readlane->SGPR hazards);
//  (c) <=48 v2f (96 floats) weights per wave, (256,2) budget -> arch-resident
//      (r9 showed 96-float waves get ~128 arch regs), no AGPR read tax;
//  (d) 1024 blocks x 4 waves = 4096 waves = 3-4 waves/SIMD occupancy.
// Roles & skew at iter t:
//  W0: kh2 k=0..31 partial of m(t-2) -> part0          (P phase)
//  W1: kh2 k=32..63 partial in regs (P); combine + gates -> h2(t-2), h2s (G)
//  W2: GRU1: h1(t) from h1s[(t-1)&1], writes h1s[t&1]  (P, t<TT); P1 prefetch
//  W3: x(t-1) = h1(t-1)*kx2 + b2[0] -> xq[(t-1)&1]     (P)
// LDS safety (all verified in r7/r9): h2s written G(t), read P(t+1);
// h1s parity slot written P(t), read P(t+1)/P(t+2) before rewrite at P(t+2)
// ... rewrite happens after both reads (2 barriers); xq slot written P(t),
// read G(t+1), rewritten P(t+2); part0 written P(t), read G(t) (1 barrier),
// rewritten P(t+1). Warmup: all state zero-init; combine guarded t>=2;
// W2 guarded t<TT; stale tail values never consumed.
__global__ __launch_bounds__(256, 2)
void rnn_main(const int* __restrict__ tokens, const float* __restrict__ P1,
              const float* __restrict__ kh1, const float* __restrict__ b1,
              const float* __restrict__ kx2, const float* __restrict__ kh2,
              const float* __restrict__ b2, const float* __restrict__ wg,
              const float* __restrict__ bg, const float* __restrict__ wd,
              const float* __restrict__ bd, float* __restrict__ out) {
    const int lane = threadIdx.x & 63;
    const int wv   = threadIdx.x >> 6;
    const int row  = blockIdx.x;
    const int l32  = lane & 31;
    const int* __restrict__ trow = tokens + row * TT;

    __shared__ __align__(16) float h2s[64];
    __shared__ __align__(16) float h1s[2][32];
    __shared__ float4 xq[2][64];
    __shared__ float4 part0[64];

    if (threadIdx.x < 64) h2s[threadIdx.x] = 0.f;
    else if (threadIdx.x < 128) ((float*)h1s)[threadIdx.x - 64] = 0.f;

    // ---- per-wave weight pairs (max 48 v2f = 96 floats) ----
    v2f w[48];
    float f0 = 0.f, f1 = 0.f, f2 = 0.f;
    if (wv == 0) {
        #pragma unroll
        for (int p = 0; p < 16; ++p) {
            w[3*p]   = mk2(kh2[(2*p)*192 + lane],       kh2[(2*p+1)*192 + lane]);
            w[3*p+1] = mk2(kh2[(2*p)*192 + 64 + lane],  kh2[(2*p+1)*192 + 64 + lane]);
            w[3*p+2] = mk2(kh2[(2*p)*192 + 128 + lane], kh2[(2*p+1)*192 + 128 + lane]);
        }
    } else if (wv == 1) {
        #pragma unroll
        for (int p = 0; p < 16; ++p) {
            w[3*p]   = mk2(kh2[(32+2*p)*192 + lane],       kh2[(33+2*p)*192 + lane]);
            w[3*p+1] = mk2(kh2[(32+2*p)*192 + 64 + lane],  kh2[(33+2*p)*192 + 64 + lane]);
            w[3*p+2] = mk2(kh2[(32+2*p)*192 + 128 + lane], kh2[(33+2*p)*192 + 128 + lane]);
        }
        f0 = b2[192 + lane]; f1 = b2[256 + lane]; f2 = b2[320 + lane];
    } else if (wv == 2) {
        #pragma unroll
        for (int p = 0; p < 16; ++p) {
            w[p]      = mk2(kh1[(2*p)*96 + lane], kh1[(2*p+1)*96 + lane]);
            w[16 + p] = (lane < 32) ? mk2(kh1[(2*p)*96 + 64 + lane], kh1[(2*p+1)*96 + 64 + lane])
                                    : mk2(0.f, 0.f);
        }
        f0 = b1[96 + lane];
        f1 = (lane < 32) ? b1[160 + lane] : 0.f;
    } else {
        #pragma unroll
        for (int p = 0; p < 16; ++p) {
            w[3*p]   = mk2(kx2[(2*p)*192 + lane],       kx2[(2*p+1)*192 + lane]);
            w[3*p+1] = mk2(kx2[(2*p)*192 + 64 + lane],  kx2[(2*p+1)*192 + 64 + lane]);
            w[3*p+2] = mk2(kx2[(2*p)*192 + 128 + lane], kx2[(2*p+1)*192 + 128 + lane]);
        }
        f0 = b2[lane]; f1 = b2[64 + lane]; f2 = b2[128 + lane];
    }

    float h1reg = 0.f;                 // W2: own h1 unit (lanes<32 valid)
    float h2reg = 0.f;                 // W1: full h2 vector
    v2f mzp, mrp, mhp;                 // W1 partial pairs (persist P->G)
    float pz = 0.f, pr = 0.f, ph = 0.f;
    int tok1 = 0;
    if (wv == 2) {
        const float* __restrict__ p = P1 + trow[0] * 96;
        pz = p[l32]; pr = p[32 + l32]; ph = p[64 + l32];
        tok1 = trow[1];
    }

    __syncthreads();

    #pragma unroll 1
    for (int t = 0; t <= TT + 1; ++t) {
        const int par = (t + 1) & 1;   // parity slot holding h1(t-1)
        // ---------------- P phase ----------------
        if (wv == 0) {
            const v4f* __restrict__ h2v = reinterpret_cast<const v4f*>(h2s);
            v2f az = mk2(0.f, 0.f), ar = az, ah = az;
            #pragma unroll
            for (int kc = 0; kc < 8; ++kc) {
                v4f hb = h2v[kc];
                v2f lo = hb.xy, hi = hb.zw;
                pkfma(az, lo, w[6*kc]);     pkfma(ar, lo, w[6*kc+1]); pkfma(ah, lo, w[6*kc+2]);
                pkfma(az, hi, w[6*kc+3]);   pkfma(ar, hi, w[6*kc+4]); pkfma(ah, hi, w[6*kc+5]);
            }
            part0[lane] = make_float4(az.x + az.y, ar.x + ar.y, ah.x + ah.y, 0.f);
        } else if (wv == 1) {
            const v4f* __restrict__ h2v = reinterpret_cast<const v4f*>(h2s);
            mzp = mk2(0.f, 0.f); mrp = mzp; mhp = mzp;
            #pragma unroll
            for (int kc = 0; kc < 8; ++kc) {
                v4f hb = h2v[8 + kc];
                v2f lo = hb.xy, hi = hb.zw;
                pkfma(mzp, lo, w[6*kc]);    pkfma(mrp, lo, w[6*kc+1]); pkfma(mhp, lo, w[6*kc+2]);
                pkfma(mzp, hi, w[6*kc+3]);  pkfma(mrp, hi, w[6*kc+4]); pkfma(mhp, hi, w[6*kc+5]);
            }
        } else if (wv == 2) {
            if (t < TT) {
                const float* __restrict__ pn = P1 + tok1 * 96;
                float pzn = pn[l32], prn = pn[32 + l32], phn = pn[64 + l32];
                int tokn = trow[(t + 2 < TT) ? (t + 2) : (TT - 1)];
                const v4f* __restrict__ h1v = reinterpret_cast<const v4f*>(h1s[par]);
                v2f az = mk2(0.f, 0.f), ah = az;
                #pragma unroll
                for (int kc = 0; kc < 8; ++kc) {
                    v4f hb = h1v[kc];
                    v2f lo = hb.xy, hi = hb.zw;
                    pkfma(az, lo, w[2*kc]);      pkfma(az, hi, w[2*kc+1]);
                    pkfma(ah, lo, w[16 + 2*kc]); pkfma(ah, hi, w[16 + 2*kc+1]);
                }
                float azs = az.x + az.y + f0;
                float ahs = ah.x + ah.y + f1;
                float ra  = __shfl_xor(azs, 32);   // r-preact to lanes 0..31
                float z1  = sigmf(pz + azs);
                float g1  = sigmf(pr + ra);
                float hh1 = tanhf_fast(ph + g1 * ahs);
                h1reg = z1 * h1reg + (1.f - z1) * hh1;   // h1(t)
                if (lane < 32) h1s[t & 1][lane] = h1reg;
                pz = pzn; pr = prn; ph = phn; tok1 = tokn;
            }
        } else {
            const v4f* __restrict__ h1v = reinterpret_cast<const v4f*>(h1s[par]);
            v2f xz = mk2(0.f, 0.f), xr = xz, xh = xz;
            #pragma unroll
            for (int kc = 0; kc < 8; ++kc) {
                v4f hb = h1v[kc];
                v2f lo = hb.xy, hi = hb.zw;
                pkfma(xz, lo, w[6*kc]);     pkfma(xr, lo, w[6*kc+1]); pkfma(xh, lo, w[6*kc+2]);
                pkfma(xz, hi, w[6*kc+3]);   pkfma(xr, hi, w[6*kc+4]); pkfma(xh, hi, w[6*kc+5]);
            }
            xq[(t + 1) & 1][lane] = make_float4(xz.x + xz.y + f0, xr.x + xr.y + f1,
                                                xh.x + xh.y + f2, 0.f);
        }
        __syncthreads();
        // ---------------- G phase ----------------
        if (wv == 1 && t >= 2) {
            float4 pa = part0[lane];
            float4 x  = xq[t & 1][lane];               // x(t-2)
            float mzs = mzp.x + mzp.y + f0;
            float mrs = mrp.x + mrp.y + f1;
            float mhs = mhp.x + mhp.y + f2;
            float z2  = sigmf(x.x + pa.x + mzs);
            float r2  = sigmf(x.y + pa.y + mrs);
            float hh2 = tanhf_fast(x.z + r2 * (pa.z + mhs));   // reset after rec mm
            h2reg = z2 * h2reg + (1.f - z2) * hh2;             // h2(t-2)
            h2s[lane] = h2reg;
        }
        __syncthreads();
    }

    // ---- tail: GLU + dense head on W1 (holds h2(TT-1)) ----
    if (wv == 1) {
        float a0 = bg[lane], a1 = bg[64 + lane], a2 = bg[128 + lane], a3 = bg[192 + lane];
        #pragma unroll
        for (int k = 0; k < 64; ++k) {
            float s = rl(h2reg, k);
            a0 += s * wg[k * 256 + lane];
            a1 += s * wg[k * 256 + 64 + lane];
            a2 += s * wg[k * 256 + 128 + lane];
            a3 += s * wg[k * 256 + 192 + lane];
        }
        float g = a0 * sigmf(a2) * wd[lane] + a1 * sigmf(a3) * wd[64 + lane];
        g += __shfl_xor(g, 32); g += __shfl_xor(g, 16); g += __shfl_xor(g, 8);
        g += __shfl_xor(g, 4);  g += __shfl_xor(g, 2);  g += __shfl_xor(g, 1);
        if (lane == 0) out[row] = sigmf(g + bd[0]);
    }
}

extern "C" void kernel_launch(void* const* d_in, const int* in_sizes, int n_in,
                              void* d_out, int out_size, void* d_ws, size_t ws_size,
                              hipStream_t stream) {
    const int*   tokens = (const int*)d_in[0];
    const float* emb = (const float*)d_in[1];
    const float* kx1 = (const float*)d_in[2];
    const float* kh1 = (const float*)d_in[3];
    const float* b1  = (const float*)d_in[4];
    const float* kx2 = (const float*)d_in[5];
    const float* kh2 = (const float*)d_in[6];
    const float* b2  = (const float*)d_in[7];
    const float* wg  = (const float*)d_in[8];
    const float* bg  = (const float*)d_in[9];
    const float* wd  = (const float*)d_in[10];
    const float* bd  = (const float*)d_in[11];
    float* out = (float*)d_out;
    float* P1  = (float*)d_ws;   // needs 50257*96*4 = 19.3 MB of workspace

    proj_emb<<<(VV + 7) / 8, 96, 0, stream>>>(emb, kx1, b1, P1);
    rnn_main<<<BB, 256, 0, stream>>>(tokens, P1, kh1, b1, kx2, kh2, b2,
                                     wg, bg, wd, bd, out);
}

// Round 11
// 1452.449 us; speedup vs baseline: 1.1580x; 1.0040x over previous
//
#include <hip/hip_runtime.h>

#define VV 50257
#define DD 50
#define TT 1024
#define BB 1024

__device__ __forceinline__ float rl(float v, int lane) {
    return __int_as_float(__builtin_amdgcn_readlane(__float_as_int(v), lane));
}
__device__ __forceinline__ float sigmf(float x) { return 1.0f / (1.0f + __expf(-x)); }
__device__ __forceinline__ float tanhf_fast(float x) {
    float e = __expf(-2.0f * fabsf(x));
    return copysignf((1.0f - e) / (1.0f + e), x);
}

// P1[v][j] = b1[0][j] + sum_d emb[v][d] * kx1[d][j]   (one-time, ~0.5 GFLOP)
__global__ void proj_emb(const float* __restrict__ emb, const float* __restrict__ kx1,
                         const float* __restrict__ b1, float* __restrict__ P1) {
    int j = threadIdx.x;             // 0..95
    int v0 = blockIdx.x * 8;
    #pragma unroll 1
    for (int vv = 0; vv < 8; ++vv) {
        int v = v0 + vv;
        if (v >= VV) return;
        float acc = b1[j];
        #pragma unroll
        for (int d = 0; d < DD; ++d)
            acc += emb[v * DD + d] * kx1[d * 96 + j];
        P1[v * 96 + j] = acc;
    }
}

// DECOUPLED producer/consumer, ZERO per-step barriers (r8 math, verified absmax 0).
//  Wave B (wv=1, producer): GRU1 recurrence + x(t)=h1(t)·kx2+b2[0]. Pure serial
//    chain, reads nothing from A. Writes x(t) into an 8-deep LDS ring, publishes
//    prod=t+1 (lane 0) after a __threadfence_block().
//  Wave A (wv=0, consumer): GRU2. Polls prod>=t+1 (no-op after warmup since B's
//    chain is shorter and runs ahead), reads x(t) FIRST (latency hidden under the
//    64-readlane kh2 matvec), gates -> h2(t), publishes cons=t+1.
//  Flow control: B overwrites slot t&7 only after cons >= t-7 (bounded buffer,
//  no circular wait -> no deadlock). Ordering: data-write -> threadfence_block
//  (lgkmcnt drain) -> flag-write; consumer polls flag (volatile), fence, reads.
//  Rationale (r0-r10 ledger): wall/step was ~3000-3500 cyc across variants whose
//  issue work ranged 500-2300 cyc -> lockstep barrier rendezvous, not issue, was
//  the wall. The A<-B dependency is one-directional, so the barrier is removable.
__global__ __launch_bounds__(128, 1)
void rnn_main(const int* __restrict__ tokens, const float* __restrict__ P1,
              const float* __restrict__ kh1, const float* __restrict__ b1,
              const float* __restrict__ kx2, const float* __restrict__ kh2,
              const float* __restrict__ b2, const float* __restrict__ wg,
              const float* __restrict__ bg, const float* __restrict__ wd,
              const float* __restrict__ bd, float* __restrict__ out) {
    const int lane = threadIdx.x & 63;
    const int wv   = threadIdx.x >> 6;        // 0 = GRU2 consumer, 1 = GRU1 producer
    const int row  = blockIdx.x;
    const int l32  = lane & 31;
    const int* __restrict__ trow = tokens + row * TT;

    __shared__ float4 xb[8][64];              // x-triple ring, 8 deep
    __shared__ int    prod;                   // B: number of x's published
    __shared__ int    cons;                   // A: number of x's consumed

    if (threadIdx.x == 0) { prod = 0; cons = 0; }

    float w[192];
    float f0, f1, f2, f3 = 0.f, f4 = 0.f;     // role-dependent biases

    if (wv == 0) {
        // kh2 columns: z=lane, r=64+lane, h=128+lane, interleaved by k
        #pragma unroll
        for (int k = 0; k < 64; ++k) {
            w[3 * k]     = kh2[k * 192 + lane];
            w[3 * k + 1] = kh2[k * 192 + 64 + lane];
            w[3 * k + 2] = kh2[k * 192 + 128 + lane];
        }
        f0 = b2[192 + lane];                  // recurrent biases b2[1]
        f1 = b2[256 + lane];
        f2 = b2[320 + lane];
    } else {
        // kh1: col lane (z for lane<32, r for lane>=32); h-col 64+lane for lane<32
        // kx2: 3 cols interleaved at w[64..191]
        #pragma unroll
        for (int k = 0; k < 32; ++k) {
            w[k]          = kh1[k * 96 + lane];
            w[32 + k]     = (lane < 32) ? kh1[k * 96 + 64 + lane] : 0.f;
            w[64 + 3 * k] = kx2[k * 192 + lane];
            w[65 + 3 * k] = kx2[k * 192 + 64 + lane];
            w[66 + 3 * k] = kx2[k * 192 + 128 + lane];
        }
        f0 = b1[96 + lane];                   // GRU1 recurrent z/r bias
        f1 = (lane < 32) ? b1[160 + lane] : 0.f;   // GRU1 recurrent h bias
        f2 = b2[lane];                        // input-proj biases b2[0]
        f3 = b2[64 + lane];
        f4 = b2[128 + lane];
    }

    __syncthreads();                          // the only barrier: flag init

    if (wv == 1) {
        // ---------------- producer: GRU1 + projection ----------------
        float h1 = 0.f;
        float pz, pr, ph;
        {
            const float* __restrict__ p = P1 + trow[0] * 96;
            pz = p[l32]; pr = p[32 + l32]; ph = p[64 + l32];
        }
        int tok1 = trow[1];

        #pragma unroll 1
        for (int t = 0; t < TT; ++t) {
            // flow control: slot t&7 must be consumed (x(t-8) read => cons >= t-7)
            if (t >= 8) {
                int need = t - 7;
                while (*(volatile int*)&cons < need) { __builtin_amdgcn_s_sleep(1); }
                __threadfence_block();
            }
            // prefetch p(t+1), token(t+2) (issue early, consumed next iter)
            const float* __restrict__ pn = P1 + tok1 * 96;
            float pzn = pn[l32], prn = pn[32 + l32], phn = pn[64 + l32];
            int tokn = trow[(t + 2 < TT) ? (t + 2) : (TT - 1)];
            // GRU1 recurrence: h1(t-1) -> h1(t)
            float az = f0, ah = f1;
            #pragma unroll
            for (int k = 0; k < 32; ++k) {
                float s = rl(h1, k);
                az += s * w[k];
                ah += s * w[32 + k];
            }
            float ra  = __shfl_xor(az, 32);   // r-preact to lanes 0..31
            float z1  = sigmf(pz + az);
            float g1  = sigmf(pr + ra);
            float hh1 = tanhf_fast(ph + g1 * ah);
            h1 = z1 * h1 + (1.f - z1) * hh1;
            // x(t) = h1(t)·kx2 + b2[0]
            float xz = f2, xr = f3, xh = f4;
            #pragma unroll
            for (int k = 0; k < 32; ++k) {
                float s = rl(h1, k);
                xz += s * w[64 + 3 * k];
                xr += s * w[65 + 3 * k];
                xh += s * w[66 + 3 * k];
            }
            xb[t & 7][lane] = make_float4(xz, xr, xh, 0.f);
            __threadfence_block();            // drain data writes before flag
            if (lane == 0) *(volatile int*)&prod = t + 1;
            pz = pzn; pr = prn; ph = phn; tok1 = tokn;
        }
        return;                               // producer done
    }

    // ---------------- consumer: GRU2 + head ----------------
    float h2 = 0.f;
    #pragma unroll 1
    for (int t = 0; t < TT; ++t) {
        // wait for x(t) (rarely spins after warmup), read it EARLY
        while (*(volatile int*)&prod < t + 1) { __builtin_amdgcn_s_sleep(1); }
        __threadfence_block();
        float4 x = xb[t & 7][lane];
        // m(t) = h2(t-1)·kh2 + b2[1]  (x-read latency hides under this)
        float mz = f0, mr = f1, mh = f2;
        #pragma unroll
        for (int k = 0; k < 64; ++k) {
            float s = rl(h2, k);
            mz += s * w[3 * k];
            mr += s * w[3 * k + 1];
            mh += s * w[3 * k + 2];
        }
        float z2  = sigmf(x.x + mz);
        float r2  = sigmf(x.y + mr);
        float hh2 = tanhf_fast(x.z + r2 * mh);   // reset after recurrent matmul
        h2 = z2 * h2 + (1.f - z2) * hh2;
        __threadfence_block();                // x fully consumed before freeing slot
        if (lane == 0) *(volatile int*)&cons = t + 1;
    }

    // ---- tail: GLU + dense head ----
    float a0 = bg[lane], a1 = bg[64 + lane], a2 = bg[128 + lane], a3 = bg[192 + lane];
    #pragma unroll
    for (int k = 0; k < 64; ++k) {
        float s = rl(h2, k);
        a0 += s * wg[k * 256 + lane];
        a1 += s * wg[k * 256 + 64 + lane];
        a2 += s * wg[k * 256 + 128 + lane];
        a3 += s * wg[k * 256 + 192 + lane];
    }
    float g = a0 * sigmf(a2) * wd[lane] + a1 * sigmf(a3) * wd[64 + lane];
    g += __shfl_xor(g, 32); g += __shfl_xor(g, 16); g += __shfl_xor(g, 8);
    g += __shfl_xor(g, 4);  g += __shfl_xor(g, 2);  g += __shfl_xor(g, 1);
    if (lane == 0) out[row] = sigmf(g + bd[0]);
}

extern "C" void kernel_launch(void* const* d_in, const int* in_sizes, int n_in,
                              void* d_out, int out_size, void* d_ws, size_t ws_size,
                              hipStream_t stream) {
    const int*   tokens = (const int*)d_in[0];
    const float* emb = (const float*)d_in[1];
    const float* kx1 = (const float*)d_in[2];
    const float* kh1 = (const float*)d_in[3];
    const float* b1  = (const float*)d_in[4];
    const float* kx2 = (const float*)d_in[5];
    const float* kh2 = (const float*)d_in[6];
    const float* b2  = (const float*)d_in[7];
    const float* wg  = (const float*)d_in[8];
    const float* bg  = (const float*)d_in[9];
    const float* wd  = (const float*)d_in[10];
    const float* bd  = (const float*)d_in[11];
    float* out = (float*)d_out;
    float* P1  = (float*)d_ws;   // needs 50257*96*4 = 19.3 MB of workspace

    proj_emb<<<(VV + 7) / 8, 96, 0, stream>>>(emb, kx1, b1, P1);
    rnn_main<<<BB, 128, 0, stream>>>(tokens, P1, kh1, b1, kx2, kh2, b2,
                                     wg, bg, wd, bd, out);
}

// Round 12
// 1286.498 us; speedup vs baseline: 1.3074x; 1.1290x over previous
//
#include <hip/hip_runtime.h>

#define VV 50257
#define DD 50
#define TT 1024
#define BB 1024

__device__ __forceinline__ float rl(float v, int lane) {
    return __int_as_float(__builtin_amdgcn_readlane(__float_as_int(v), lane));
}
__device__ __forceinline__ float sigmf(float x) { return 1.0f / (1.0f + __expf(-x)); }
__device__ __forceinline__ float tanhf_fast(float x) {
    float e = __expf(-2.0f * fabsf(x));
    return copysignf((1.0f - e) / (1.0f + e), x);
}

// P1[v][j] = b1[0][j] + sum_d emb[v][d] * kx1[d][j]   (one-time, ~0.5 GFLOP)
__global__ void proj_emb(const float* __restrict__ emb, const float* __restrict__ kx1,
                         const float* __restrict__ b1, float* __restrict__ P1) {
    int j = threadIdx.x;             // 0..95
    int v0 = blockIdx.x * 8;
    #pragma unroll 1
    for (int vv = 0; vv < 8; ++vv) {
        int v = v0 + vv;
        if (v >= VV) return;
        float acc = b1[j];
        #pragma unroll
        for (int d = 0; d < DD; ++d)
            acc += emb[v * DD + d] * kx1[d * 96 + j];
        P1[v * 96 + j] = acc;
    }
}

// r8 kernel (best: 1282 us, absmax 0.0) with ONE change: amdgpu_waves_per_eu(2,2).
// Ledger r1-r11: every variant's VGPR_Count lands 108-152 arch for 200+ float
// live sets -> the allocator targets default occupancy (3-4 waves/EU = ~512/144)
// and shunts weights into AGPRs; VALU can't source AGPRs, so each weight use
// pays a v_accvgpr_read (~350 extra VALU/row-step = the measured ~2x issue
// bloat). launch_bounds' 2nd arg sets only MIN waves/EU (r3 proved min=2
// doesn't help). Setting MAX=2 removes the allocator's incentive to squeeze:
// with occupancy capped at 2/SIMD (which equals our actual residency,
// 2048 waves / 1024 SIMDs), it can allocate the full ~230-float live set in
// architected VGPRs. Gate observable: VGPR_Count ~220-256.
//  Wave B (wv=1): GRU1(t+1) AND x(t+1)=h1(t+1)·kx2+b2[0], both pre-barrier.
//  Wave A (wv=0): pre: m(t)=h2(t-1)·kh2+b2[1]; post: gates -> h2(t).
//  Ring safety: slot (t+1)&3 written pre-barrier at iter t, read post-barrier
//  at iter t+1, rewritten at iter t+4 (>=2 barriers after the read).
__global__ __launch_bounds__(128) __attribute__((amdgpu_waves_per_eu(2, 2)))
void rnn_main(const int* __restrict__ tokens, const float* __restrict__ P1,
              const float* __restrict__ kh1, const float* __restrict__ b1,
              const float* __restrict__ kx2, const float* __restrict__ kh2,
              const float* __restrict__ b2, const float* __restrict__ wg,
              const float* __restrict__ bg, const float* __restrict__ wd,
              const float* __restrict__ bd, float* __restrict__ out) {
    const int lane = threadIdx.x & 63;
    const int wv   = threadIdx.x >> 6;        // 0 = GRU2 wave, 1 = GRU1+proj wave
    const int row  = blockIdx.x;
    const int l32  = lane & 31;
    const int* __restrict__ trow = tokens + row * TT;

    __shared__ float4 xb[4][64];              // ring of x-triples

    float w[192];
    float f0, f1, f2, f3 = 0.f, f4 = 0.f;     // role-dependent biases

    if (wv == 0) {
        // kh2 columns: z=lane, r=64+lane, h=128+lane, interleaved by k
        #pragma unroll
        for (int k = 0; k < 64; ++k) {
            w[3 * k]     = kh2[k * 192 + lane];
            w[3 * k + 1] = kh2[k * 192 + 64 + lane];
            w[3 * k + 2] = kh2[k * 192 + 128 + lane];
        }
        f0 = b2[192 + lane];                  // recurrent biases b2[1]
        f1 = b2[256 + lane];
        f2 = b2[320 + lane];
    } else {
        // kh1: col lane (z for lane<32, r for lane>=32); h-col 64+lane for lane<32
        // kx2: 3 cols interleaved at w[64..191]
        #pragma unroll
        for (int k = 0; k < 32; ++k) {
            w[k]          = kh1[k * 96 + lane];
            w[32 + k]     = (lane < 32) ? kh1[k * 96 + 64 + lane] : 0.f;
            w[64 + 3 * k] = kx2[k * 192 + lane];
            w[65 + 3 * k] = kx2[k * 192 + 64 + lane];
            w[66 + 3 * k] = kx2[k * 192 + 128 + lane];
        }
        f0 = b1[96 + lane];                   // GRU1 recurrent z/r bias
        f1 = (lane < 32) ? b1[160 + lane] : 0.f;   // GRU1 recurrent h bias
        f2 = b2[lane];                        // input-proj biases b2[0]
        f3 = b2[64 + lane];
        f4 = b2[128 + lane];
    }

    float h1 = 0.f, h2 = 0.f;
    float pz = 0.f, pr = 0.f, ph = 0.f;
    int tokc = 0;
    if (wv == 1) {                            // p-triple for GRU1 step 0
        const float* __restrict__ p = P1 + trow[0] * 96;
        pz = p[l32]; pr = p[32 + l32]; ph = p[64 + l32];
        tokc = trow[1];                       // token for p(t+2) prefetch at t=-1
    }

    float mz, mr, mh;

    #pragma unroll 1
    for (int t = -1; t < TT; ++t) {
        // ---------------- pre-barrier ----------------
        if (wv == 0) {
            if (t >= 0) {
                mz = f0; mr = f1; mh = f2;
                #pragma unroll
                for (int k = 0; k < 64; ++k) {
                    float s = rl(h2, k);
                    mz += s * w[3 * k];
                    mr += s * w[3 * k + 1];
                    mh += s * w[3 * k + 2];
                }
            }
        } else if (t + 1 < TT) {
            // prefetch p(t+2) and token(t+3)
            const float* __restrict__ pn = P1 + tokc * 96;
            float pzn = pn[l32], prn = pn[32 + l32], phn = pn[64 + l32];
            int tokn = trow[(t + 3 < TT) ? (t + 3) : (TT - 1)];
            // GRU1 recurrence: h1(t) -> h1(t+1)
            float az = f0, ah = f1;
            #pragma unroll
            for (int k = 0; k < 32; ++k) {
                float s = rl(h1, k);
                az += s * w[k];
                ah += s * w[32 + k];
            }
            float ra  = __shfl_xor(az, 32);   // r-preact to lanes 0..31
            float z1  = sigmf(pz + az);
            float g1  = sigmf(pr + ra);
            float hh1 = tanhf_fast(ph + g1 * ah);
            h1 = z1 * h1 + (1.f - z1) * hh1;
            // x(t+1) = h1(t+1)·kx2 + b2[0]  -> ring slot (t+1)&3
            float xz = f2, xr = f3, xh = f4;
            #pragma unroll
            for (int k = 0; k < 32; ++k) {
                float s = rl(h1, k);
                xz += s * w[64 + 3 * k];
                xr += s * w[65 + 3 * k];
                xh += s * w[66 + 3 * k];
            }
            xb[(t + 1) & 3][lane] = make_float4(xz, xr, xh, 0.f);
            pz = pzn; pr = prn; ph = phn; tokc = tokn;
        }
        __syncthreads();
        // ---------------- post-barrier ----------------
        if (wv == 0 && t >= 0) {
            float4 x  = xb[t & 3][lane];
            float z2  = sigmf(x.x + mz);
            float r2  = sigmf(x.y + mr);
            float hh2 = tanhf_fast(x.z + r2 * mh);   // reset after recurrent mm
            h2 = z2 * h2 + (1.f - z2) * hh2;
        }
    }

    // ---- tail: GLU + dense head, wave A only (holds h2) ----
    if (wv == 0) {
        float a0 = bg[lane], a1 = bg[64 + lane], a2 = bg[128 + lane], a3 = bg[192 + lane];
        #pragma unroll
        for (int k = 0; k < 64; ++k) {
            float s = rl(h2, k);
            a0 += s * wg[k * 256 + lane];
            a1 += s * wg[k * 256 + 64 + lane];
            a2 += s * wg[k * 256 + 128 + lane];
            a3 += s * wg[k * 256 + 192 + lane];
        }
        float g = a0 * sigmf(a2) * wd[lane] + a1 * sigmf(a3) * wd[64 + lane];
        g += __shfl_xor(g, 32); g += __shfl_xor(g, 16); g += __shfl_xor(g, 8);
        g += __shfl_xor(g, 4);  g += __shfl_xor(g, 2);  g += __shfl_xor(g, 1);
        if (lane == 0) out[row] = sigmf(g + bd[0]);
    }
}

extern "C" void kernel_launch(void* const* d_in, const int* in_sizes, int n_in,
                              void* d_out, int out_size, void* d_ws, size_t ws_size,
                              hipStream_t stream) {
    const int*   tokens = (const int*)d_in[0];
    const float* emb = (const float*)d_in[1];
    const float* kx1 = (const float*)d_in[2];
    const float* kh1 = (const float*)d_in[3];
    const float* b1  = (const float*)d_in[4];
    const float* kx2 = (const float*)d_in[5];
    const float* kh2 = (const float*)d_in[6];
    const float* b2  = (const float*)d_in[7];
    const float* wg  = (const float*)d_in[8];
    const float* bg  = (const float*)d_in[9];
    const float* wd  = (const float*)d_in[10];
    const float* bd  = (const float*)d_in[11];
    float* out = (float*)d_out;
    float* P1  = (float*)d_ws;   // needs 50257*96*4 = 19.3 MB of workspace

    proj_emb<<<(VV + 7) / 8, 96, 0, stream>>>(emb, kx1, b1, P1);
    rnn_main<<<BB, 128, 0, stream>>>(tokens, P1, kh1, b1, kx2, kh2, b2,
                                     wg, bg, wd, bd, out);
}

// Round 13
// 1024.850 us; speedup vs baseline: 1.6411x; 1.2553x over previous
//
#include <hip/hip_runtime.h>

#define VV 50257
#define DD 50
#define TT 1024
#define BB 1024

typedef float v4f __attribute__((ext_vector_type(4)));

__device__ __forceinline__ float rl(float v, int lane) {
    return __int_as_float(__builtin_amdgcn_readlane(__float_as_int(v), lane));
}
__device__ __forceinline__ float sigmf(float x) { return 1.0f / (1.0f + __expf(-x)); }
__device__ __forceinline__ float tanhf_fast(float x) {
    float e = __expf(-2.0f * fabsf(x));
    return copysignf((1.0f - e) / (1.0f + e), x);
}

// P1[v][j] = b1[0][j] + sum_d emb[v][d] * kx1[d][j]   (one-time, ~0.5 GFLOP)
__global__ void proj_emb(const float* __restrict__ emb, const float* __restrict__ kx1,
                         const float* __restrict__ b1, float* __restrict__ P1) {
    int j = threadIdx.x;             // 0..95
    int v0 = blockIdx.x * 8;
    #pragma unroll 1
    for (int vv = 0; vv < 8; ++vv) {
        int v = v0 + vv;
        if (v >= VV) return;
        float acc = b1[j];
        #pragma unroll
        for (int d = 0; d < DD; ++d)
            acc += emb[v * DD + d] * kx1[d * 96 + j];
        P1[v * 96 + j] = acc;
    }
}

// r12/r8 two-wave structure (best: 1282 us, absmax 0.0) with ONE isolated change:
// state broadcast via uniform-address ds_read_b128 from tiny LDS buffers instead
// of v_readlane. Rationale: r10 showed LDS-broadcast cuts busy-cycles ~35%, but
// was bundled with a slower 4-wave structure; readlane variants all plateau at
// the same busy level (suspected v_readlane->SGPR->VALU hazard x128/step).
//  Wave A (wv=0): pre: m(t)=h2(t-1)·kh2+b2[1], h2(t-1) broadcast from h2s
//    (written by A itself at post of t-1; same-wave lgkmcnt ordering, no extra
//    barrier). post: read x(t) from ring, gates -> h2(t), write h2s.
//  Wave B (wv=1): pre at iter t: broadcast h1(t) from h1s (written by B at
//    iter t-1); compute x(t)=h1(t)·kx2+b2[0] -> ring slot t&3 (t>=0) AND
//    h1(t+1) via GRU1 gates (t<TT-1; per-lane h1 kept in register as before,
//    LDS copy only for broadcast). Projection re-skewed by one iter vs r12 so
//    both matvecs consume ONE broadcast read.
//  Ring safety: slot t&3 written pre-barrier of t, read post-barrier of t
//  (1 barrier between), rewritten pre of t+4 (4 barriers after the read).
//  Warmup: h1s/h2s zero-init by their own wave; at t=-1 A idles, B computes
//  h1(0) from h1(-1)=0 (no x). A first reads h2s at t=0 (init value = h2(-1)=0).
__global__ __launch_bounds__(128, 1)
void rnn_main(const int* __restrict__ tokens, const float* __restrict__ P1,
              const float* __restrict__ kh1, const float* __restrict__ b1,
              const float* __restrict__ kx2, const float* __restrict__ kh2,
              const float* __restrict__ b2, const float* __restrict__ wg,
              const float* __restrict__ bg, const float* __restrict__ wd,
              const float* __restrict__ bd, float* __restrict__ out) {
    const int lane = threadIdx.x & 63;
    const int wv   = threadIdx.x >> 6;        // 0 = GRU2 wave, 1 = GRU1+proj wave
    const int row  = blockIdx.x;
    const int l32  = lane & 31;
    const int* __restrict__ trow = tokens + row * TT;

    __shared__ float4 xb[4][64];              // ring of x-triples
    __shared__ __align__(16) float h2s[64];   // h2 broadcast buffer (wave A only)
    __shared__ __align__(16) float h1s[32];   // h1 broadcast buffer (wave B only)

    float w[192];
    float f0, f1, f2, f3 = 0.f, f4 = 0.f;     // role-dependent biases

    if (wv == 0) {
        h2s[lane] = 0.f;                      // h2(-1) = 0
        // kh2 columns: z=lane, r=64+lane, h=128+lane, interleaved by k
        #pragma unroll
        for (int k = 0; k < 64; ++k) {
            w[3 * k]     = kh2[k * 192 + lane];
            w[3 * k + 1] = kh2[k * 192 + 64 + lane];
            w[3 * k + 2] = kh2[k * 192 + 128 + lane];
        }
        f0 = b2[192 + lane];                  // recurrent biases b2[1]
        f1 = b2[256 + lane];
        f2 = b2[320 + lane];
    } else {
        if (lane < 32) h1s[lane] = 0.f;       // h1(-1) = 0
        // kh1: col lane (z for lane<32, r for lane>=32); h-col 64+lane for lane<32
        // kx2: 3 cols interleaved at w[64..191]
        #pragma unroll
        for (int k = 0; k < 32; ++k) {
            w[k]          = kh1[k * 96 + lane];
            w[32 + k]     = (lane < 32) ? kh1[k * 96 + 64 + lane] : 0.f;
            w[64 + 3 * k] = kx2[k * 192 + lane];
            w[65 + 3 * k] = kx2[k * 192 + 64 + lane];
            w[66 + 3 * k] = kx2[k * 192 + 128 + lane];
        }
        f0 = b1[96 + lane];                   // GRU1 recurrent z/r bias
        f1 = (lane < 32) ? b1[160 + lane] : 0.f;   // GRU1 recurrent h bias
        f2 = b2[lane];                        // input-proj biases b2[0]
        f3 = b2[64 + lane];
        f4 = b2[128 + lane];
    }

    float h1 = 0.f, h2 = 0.f;                 // per-lane state registers
    float pz = 0.f, pr = 0.f, ph = 0.f;
    int tokc = 0;
    if (wv == 1) {                            // p-triple for GRU1 step 0
        const float* __restrict__ p = P1 + trow[0] * 96;
        pz = p[l32]; pr = p[32 + l32]; ph = p[64 + l32];
        tokc = trow[1];                       // token for p(t+2) prefetch at t=-1
    }

    float mz, mr, mh;

    #pragma unroll 1
    for (int t = -1; t < TT; ++t) {
        // ---------------- pre-barrier ----------------
        if (wv == 0) {
            if (t >= 0) {
                // m(t) = h2(t-1)·kh2 + b2[1], h2(t-1) broadcast from LDS
                const v4f* __restrict__ h2v = reinterpret_cast<const v4f*>(h2s);
                mz = f0; mr = f1; mh = f2;
                #pragma unroll
                for (int kc = 0; kc < 16; ++kc) {
                    v4f hb = h2v[kc];
                    const int b = kc * 12;
                    mz += hb.x * w[b];     mr += hb.x * w[b + 1];  mh += hb.x * w[b + 2];
                    mz += hb.y * w[b + 3]; mr += hb.y * w[b + 4];  mh += hb.y * w[b + 5];
                    mz += hb.z * w[b + 6]; mr += hb.z * w[b + 7];  mh += hb.z * w[b + 8];
                    mz += hb.w * w[b + 9]; mr += hb.w * w[b + 10]; mh += hb.w * w[b + 11];
                }
            }
        } else if (t < TT) {
            // broadcast h1(t) (written by this wave at iter t-1; init for t=-1)
            const v4f* __restrict__ h1v = reinterpret_cast<const v4f*>(h1s);
            v4f hb[8];
            #pragma unroll
            for (int kc = 0; kc < 8; ++kc) hb[kc] = h1v[kc];
            if (t >= 0) {
                // x(t) = h1(t)·kx2 + b2[0]  -> ring slot t&3
                float xz = f2, xr = f3, xh = f4;
                #pragma unroll
                for (int kc = 0; kc < 8; ++kc) {
                    const int b = 64 + kc * 12;
                    xz += hb[kc].x * w[b];     xr += hb[kc].x * w[b + 1];  xh += hb[kc].x * w[b + 2];
                    xz += hb[kc].y * w[b + 3]; xr += hb[kc].y * w[b + 4];  xh += hb[kc].y * w[b + 5];
                    xz += hb[kc].z * w[b + 6]; xr += hb[kc].z * w[b + 7];  xh += hb[kc].z * w[b + 8];
                    xz += hb[kc].w * w[b + 9]; xr += hb[kc].w * w[b + 10]; xh += hb[kc].w * w[b + 11];
                }
                xb[t & 3][lane] = make_float4(xz, xr, xh, 0.f);
            }
            if (t < TT - 1) {
                // GRU1: h1(t) -> h1(t+1) using p(t+1)
                float az = f0, ah = f1;
                #pragma unroll
                for (int kc = 0; kc < 8; ++kc) {
                    az += hb[kc].x * w[4 * kc];     ah += hb[kc].x * w[32 + 4 * kc];
                    az += hb[kc].y * w[4 * kc + 1]; ah += hb[kc].y * w[32 + 4 * kc + 1];
                    az += hb[kc].z * w[4 * kc + 2]; ah += hb[kc].z * w[32 + 4 * kc + 2];
                    az += hb[kc].w * w[4 * kc + 3]; ah += hb[kc].w * w[32 + 4 * kc + 3];
                }
                float ra  = __shfl_xor(az, 32);   // r-preact to lanes 0..31
                float z1  = sigmf(pz + az);
                float g1  = sigmf(pr + ra);
                float hh1 = tanhf_fast(ph + g1 * ah);
                h1 = z1 * h1 + (1.f - z1) * hh1;  // h1(t+1) per-lane
                if (lane < 32) h1s[lane] = h1;    // publish broadcast copy
                // prefetch p(t+2), token(t+3)
                const float* __restrict__ pn = P1 + tokc * 96;
                pz = pn[l32]; pr = pn[32 + l32]; ph = pn[64 + l32];
                tokc = trow[(t + 3 < TT) ? (t + 3) : (TT - 1)];
            }
        }
        __syncthreads();
        // ---------------- post-barrier ----------------
        if (wv == 0 && t >= 0) {
            float4 x  = xb[t & 3][lane];
            float z2  = sigmf(x.x + mz);
            float r2  = sigmf(x.y + mr);
            float hh2 = tanhf_fast(x.z + r2 * mh);   // reset after recurrent mm
            h2 = z2 * h2 + (1.f - z2) * hh2;
            h2s[lane] = h2;                          // publish for next pre-phase
        }
    }

    // ---- tail: GLU + dense head, wave A only (holds h2) ----
    if (wv == 0) {
        float a0 = bg[lane], a1 = bg[64 + lane], a2 = bg[128 + lane], a3 = bg[192 + lane];
        #pragma unroll
        for (int k = 0; k < 64; ++k) {
            float s = rl(h2, k);
            a0 += s * wg[k * 256 + lane];
            a1 += s * wg[k * 256 + 64 + lane];
            a2 += s * wg[k * 256 + 128 + lane];
            a3 += s * wg[k * 256 + 192 + lane];
        }
        float g = a0 * sigmf(a2) * wd[lane] + a1 * sigmf(a3) * wd[64 + lane];
        g += __shfl_xor(g, 32); g += __shfl_xor(g, 16); g += __shfl_xor(g, 8);
        g += __shfl_xor(g, 4);  g += __shfl_xor(g, 2);  g += __shfl_xor(g, 1);
        if (lane == 0) out[row] = sigmf(g + bd[0]);
    }
}

extern "C" void kernel_launch(void* const* d_in, const int* in_sizes, int n_in,
                              void* d_out, int out_size, void* d_ws, size_t ws_size,
                              hipStream_t stream) {
    const int*   tokens = (const int*)d_in[0];
    const float* emb = (const float*)d_in[1];
    const float* kx1 = (const float*)d_in[2];
    const float* kh1 = (const float*)d_in[3];
    const float* b1  = (const float*)d_in[4];
    const float* kx2 = (const float*)d_in[5];
    const float* kh2 = (const float*)d_in[6];
    const float* b2  = (const float*)d_in[7];
    const float* wg  = (const float*)d_in[8];
    const float* bg  = (const float*)d_in[9];
    const float* wd  = (const float*)d_in[10];
    const float* bd  = (const float*)d_in[11];
    float* out = (float*)d_out;
    float* P1  = (float*)d_ws;   // needs 50257*96*4 = 19.3 MB of workspace

    proj_emb<<<(VV + 7) / 8, 96, 0, stream>>>(emb, kx1, b1, P1);
    rnn_main<<<BB, 128, 0, stream>>>(tokens, P1, kh1, b1, kx2, kh2, b2,
                                     wg, bg, wd, bd, out);
}